// Round 3
// baseline (207.436 us; speedup 1.0000x reference)
//
#include <hip/hip_runtime.h>
#include <hip/hip_bf16.h>

typedef __bf16 bf16_t;
typedef __bf16 bf16x8 __attribute__((ext_vector_type(8)));
typedef __bf16 bf16x4 __attribute__((ext_vector_type(4)));
typedef float  f32x4  __attribute__((ext_vector_type(4)));
typedef float  f32x16 __attribute__((ext_vector_type(16)));

#define B_ 8
#define C_ 256
#define L_ 4096
#define M_ 2048

__device__ __forceinline__ const bf16x8* ldg8(const bf16_t* p) {
    return reinterpret_cast<const bf16x8*>(p);
}

typedef __attribute__((address_space(3))) void as3_void;
typedef __attribute__((address_space(1))) const void as1_cvoid;

__device__ __forceinline__ void gload_lds16(const void* g, void* l) {
    __builtin_amdgcn_global_load_lds((as1_cvoid*)g, (as3_void*)l, 16, 0, 0);
}

__device__ __forceinline__ unsigned packbf(float a, float b) {
    unsigned short ua = __builtin_bit_cast(unsigned short, (bf16_t)a);
    unsigned short ub = __builtin_bit_cast(unsigned short, (bf16_t)b);
    return (unsigned)ua | ((unsigned)ub << 16);
}

// ---------------- kernel 1: weight conversion f32 -> bf16 ----------------
__global__ __launch_bounds__(256) void conv_w_kernel(
    const float* __restrict__ Wq, const float* __restrict__ Wk, const float* __restrict__ Wv,
    bf16_t* __restrict__ Wqb, bf16_t* __restrict__ Wkb, bf16_t* __restrict__ Wvb) {
    int idx = blockIdx.x * 256 + threadIdx.x;      // 0..196607
    int which = idx >> 16;
    int off = idx & 65535;
    const float* src = (which == 0) ? Wq : ((which == 1) ? Wk : Wv);
    bf16_t* dst = (which == 0) ? Wqb : ((which == 1) ? Wkb : Wvb);
    dst[off] = (bf16_t)src[off];
}

// ---------------- kernel 2: x -> xbt [B,L,C] bf16 ; xh -> xhbt [B,M,C] bf16 ----------------
__global__ __launch_bounds__(256) void prep_x_kernel(
    const float* __restrict__ x, bf16_t* __restrict__ xbt, bf16_t* __restrict__ xhbt) {
    __shared__ float tile[64][65];   // [c][l]
    const float INV_SQRT2 = 0.70710678118654752440f;
    int b = blockIdx.z, c0 = blockIdx.y * 64, l0 = blockIdx.x * 64;
    int t = threadIdx.x;
    int tr = t >> 6;      // 0..3
    int tc = t & 63;
    const float* xp = x + ((size_t)(b * C_ + c0) * L_) + l0;
#pragma unroll
    for (int i = 0; i < 16; ++i) {
        int row = i * 4 + tr;
        tile[row][tc] = xp[(size_t)row * L_ + tc];
    }
    __syncthreads();
    bf16_t* xo = xbt + ((size_t)(b * L_ + l0) * C_) + c0;
#pragma unroll
    for (int i = 0; i < 16; ++i) {
        int lr = i * 4 + tr;
        xo[(size_t)lr * C_ + tc] = (bf16_t)tile[tc][lr];
    }
    int m0 = l0 >> 1;
    bf16_t* xho = xhbt + ((size_t)(b * M_ + m0) * C_) + c0;
#pragma unroll
    for (int i = 0; i < 8; ++i) {
        int mr = i * 4 + tr;
        float v = (tile[tc][2 * mr] - tile[tc][2 * mr + 1]) * INV_SQRT2;
        xho[(size_t)mr * C_ + tc] = (bf16_t)v;
    }
}

// ---------------- kernel 3: out[b][n][o] = sum_c A[b][n][c] * W[o][c] + bias[o] ----------------
__global__ __launch_bounds__(256) void proj_nk_kernel(
    const bf16_t* __restrict__ A, const bf16_t* __restrict__ W,
    const float* __restrict__ bias, bf16_t* __restrict__ out, int N) {
    int b = blockIdx.y;
    int wave = threadIdx.x >> 6, lane = threadIdx.x & 63;
    int l15 = lane & 15, g = lane >> 4;
    int n0 = blockIdx.x * 64 + wave * 16;

    const bf16_t* Ap = A + ((size_t)(b * N + n0 + l15) * C_) + g * 8;
    bf16x8 af[8];
#pragma unroll
    for (int k = 0; k < 8; ++k) af[k] = *ldg8(Ap + k * 32);

    f32x4 acc[16];
#pragma unroll
    for (int ot = 0; ot < 16; ++ot) {
        float bb = bias[ot * 16 + l15];
        acc[ot][0] = bb; acc[ot][1] = bb; acc[ot][2] = bb; acc[ot][3] = bb;
    }
#pragma unroll
    for (int ot = 0; ot < 16; ++ot) {
        const bf16_t* Wp = W + ((size_t)(ot * 16 + l15) * C_) + g * 8;
#pragma unroll
        for (int k = 0; k < 8; ++k) {
            bf16x8 bfr = *ldg8(Wp + k * 32);
            acc[ot] = __builtin_amdgcn_mfma_f32_16x16x32_bf16(af[k], bfr, acc[ot], 0, 0, 0);
        }
    }
    bf16_t* op = out + ((size_t)(b * N + n0 + g * 4) * C_);
#pragma unroll
    for (int ot = 0; ot < 16; ++ot)
#pragma unroll
        for (int r = 0; r < 4; ++r)
            op[(size_t)r * C_ + ot * 16 + l15] = (bf16_t)acc[ot][r];
}

// ---------------- kernel 4: v'[b][o][m] = sum_c Wv[o][c] * xhbt[b][m][c] + bv[o] ----------------
__global__ __launch_bounds__(256) void proj_v_kernel(
    const bf16_t* __restrict__ xhbt, const bf16_t* __restrict__ W,
    const float* __restrict__ bias, bf16_t* __restrict__ out) {
    int b = blockIdx.z;
    int wave = threadIdx.x >> 6, lane = threadIdx.x & 63;
    int l15 = lane & 15, g = lane >> 4;
    int o0 = blockIdx.y * 64 + wave * 16;
    int m0 = blockIdx.x * 256;

    const bf16_t* Wp = W + ((size_t)(o0 + l15) * C_) + g * 8;
    bf16x8 af[8];
#pragma unroll
    for (int k = 0; k < 8; ++k) af[k] = *ldg8(Wp + k * 32);

    float bv4[4];
#pragma unroll
    for (int r = 0; r < 4; ++r) bv4[r] = bias[o0 + g * 4 + r];

    f32x4 acc[16];
#pragma unroll
    for (int mt = 0; mt < 16; ++mt) {
        acc[mt][0] = bv4[0]; acc[mt][1] = bv4[1]; acc[mt][2] = bv4[2]; acc[mt][3] = bv4[3];
    }
#pragma unroll
    for (int mt = 0; mt < 16; ++mt) {
        const bf16_t* Bp = xhbt + ((size_t)(b * M_ + m0 + mt * 16 + l15) * C_) + g * 8;
#pragma unroll
        for (int k = 0; k < 8; ++k) {
            bf16x8 bfr = *ldg8(Bp + k * 32);
            acc[mt] = __builtin_amdgcn_mfma_f32_16x16x32_bf16(af[k], bfr, acc[mt], 0, 0, 0);
        }
    }
    bf16_t* op = out + ((size_t)(b * C_ + o0 + g * 4) * M_) + m0;
#pragma unroll
    for (int mt = 0; mt < 16; ++mt)
#pragma unroll
        for (int r = 0; r < 4; ++r)
            op[(size_t)r * M_ + mt * 16 + l15] = (bf16_t)acc[mt][r];
}

// ---------------- kernel 5: flash attention, 32x32 MFMA, in-register P ----------------
// 256 threads (4 waves), Br=128 queries/block (32/wave), KT=64 keys/tile.
// S = K'(A) x Q(B) -> D[m,l] (col l = lane&31). Softmax per-lane + shfl_xor(32).
// P built in registers (pack-bf16 + shfl_xor exchange). PV: A=V[c][m] from LDS, B=P.
// K and V both double-buffered via global_load_lds with pre-swizzled source.
#define KT 64
#define NT (M_ / KT)   // 32

__global__ __launch_bounds__(256, 1) void attn_kernel(
    const bf16_t* __restrict__ qb, const bf16_t* __restrict__ kb, const bf16_t* __restrict__ vb,
    const float* __restrict__ x, const float* __restrict__ gate, float* __restrict__ out) {
    // LDS: K 2x32KB | V 2x32KB = 128KB
    __shared__ __align__(16) char smem[131072];
    char* Kbase_l = smem;
    char* Vbase_l = smem + 65536;

    const int t = threadIdx.x;
    const int wave = t >> 6, lane = t & 63;
    const int l31 = lane & 31, hi = lane >> 5;
    const int bid = blockIdx.x;
    const int b = bid & 7;          // batch -> XCD affinity
    const int lt = bid >> 3;        // 0..31
    const int l0w = lt * 128 + wave * 32;

    // ---- Q fragments in registers: qf[ks] = Q[l0w + l31][ks*16 + hi*8 .. +8] ----
    bf16x8 qf[16];
    const bf16_t* Qp = qb + ((size_t)(b * L_ + l0w + l31) * C_) + hi * 8;
#pragma unroll
    for (int ks = 0; ks < 16; ++ks) qf[ks] = *ldg8(Qp + ks * 16);

    f32x16 acc[8];
#pragma unroll
    for (int cb = 0; cb < 8; ++cb)
#pragma unroll
        for (int r = 0; r < 16; ++r) acc[cb][r] = 0.f;
    float m_run = -INFINITY, l_run = 0.f;

    // ---- staging geometry (global source pre-swizzled, LDS dest linear) ----
    const char* Kg = (const char*)(kb + (size_t)b * M_ * C_);
    const char* Vg = (const char*)(vb + (size_t)b * C_ * M_);
    int ksrc[8], vsrc[8];
#pragma unroll
    for (int i = 0; i < 8; ++i) {
        int chunk = i * 4 + wave;                 // 0..31 (1KB LDS chunks)
        int mr = chunk * 2 + (lane >> 5);         // K row 0..63
        ksrc[i] = mr * 512 + (((lane & 31) * 16) ^ ((mr & 7) << 4));
        int c = chunk * 8 + (lane >> 3);          // V row 0..255
        vsrc[i] = c * (M_ * 2) + (((lane & 7) * 16) ^ ((c & 7) << 4));
    }

    // ---- prologue: stage tile 0 into buffer 0 ----
#pragma unroll
    for (int i = 0; i < 8; ++i)
        gload_lds16(Kg + ksrc[i], Kbase_l + (i * 4 + wave) * 1024);
#pragma unroll
    for (int i = 0; i < 8; ++i)
        gload_lds16(Vg + vsrc[i], Vbase_l + (i * 4 + wave) * 1024);
    asm volatile("s_waitcnt vmcnt(0)" ::: "memory");
    __builtin_amdgcn_s_barrier();
    asm volatile("" ::: "memory");

    for (int kt = 0; kt < NT; ++kt) {
        const int cur = kt & 1;
        // ---- issue DMA for tile kt+1 into other buffers ----
        if (kt + 1 < NT) {
            const char* Kn = Kg + (size_t)(kt + 1) * 32768;
            char* Kd = Kbase_l + (cur ^ 1) * 32768;
#pragma unroll
            for (int i = 0; i < 8; ++i)
                gload_lds16(Kn + ksrc[i], Kd + (i * 4 + wave) * 1024);
            const char* Vn = Vg + (size_t)(kt + 1) * 128;   // m-offset in bytes
            char* Vd = Vbase_l + (cur ^ 1) * 32768;
#pragma unroll
            for (int i = 0; i < 8; ++i)
                gload_lds16(Vn + vsrc[i], Vd + (i * 4 + wave) * 1024);
        }

        // ---- S = K' x Q : D[m,l], 2 m-blocks x 16 k-steps ----
        const char* Kc = Kbase_l + cur * 32768;
        f32x16 s0, s1;
#pragma unroll
        for (int r = 0; r < 16; ++r) { s0[r] = 0.f; s1[r] = 0.f; }
#pragma unroll
        for (int ks = 0; ks < 16; ++ks) {
            int cb2 = ks * 32 + hi * 16;
            {
                int m = l31;
                bf16x8 a = *reinterpret_cast<const bf16x8*>(Kc + m * 512 + (cb2 ^ ((m & 7) << 4)));
                s0 = __builtin_amdgcn_mfma_f32_32x32x16_bf16(a, qf[ks], s0, 0, 0, 0);
            }
            {
                int m = 32 + l31;
                bf16x8 a = *reinterpret_cast<const bf16x8*>(Kc + m * 512 + (cb2 ^ ((m & 7) << 4)));
                s1 = __builtin_amdgcn_mfma_f32_32x32x16_bf16(a, qf[ks], s1, 0, 0, 0);
            }
        }

        // ---- online softmax over m; lanes l and l+32 share query column l ----
        float pv[32];
        float tm = -INFINITY;
#pragma unroll
        for (int r = 0; r < 16; ++r) {
            float v0 = s0[r] * 0.0625f;
            float v1 = s1[r] * 0.0625f;
            pv[r] = v0; pv[16 + r] = v1;
            tm = fmaxf(tm, fmaxf(v0, v1));
        }
        tm = fmaxf(tm, __shfl_xor(tm, 32));
        if (!__all(tm - m_run <= 8.0f)) {           // defer-max (T13)
            float m_new = fmaxf(m_run, tm);
            float corr = __expf(m_run - m_new);
#pragma unroll
            for (int cb = 0; cb < 8; ++cb)
#pragma unroll
                for (int r = 0; r < 16; ++r) acc[cb][r] *= corr;
            l_run *= corr;
            m_run = m_new;
        }
        float rs = 0.f;
#pragma unroll
        for (int i = 0; i < 32; ++i) { pv[i] = __expf(pv[i] - m_run); rs += pv[i]; }
        l_run += rs + __shfl_xor(rs, 32);

        // ---- build P B-frags in registers (k = m within tile) ----
        union PW { unsigned u[4]; bf16x8 v; };
        bf16x8 pfrag[4];
#pragma unroll
        for (int mb = 0; mb < 2; ++mb) {
            int o = mb * 16;
            unsigned Ce0 = packbf(pv[o + 0], pv[o + 1]);
            unsigned Ce1 = packbf(pv[o + 2], pv[o + 3]);
            unsigned Ce2 = packbf(pv[o + 4], pv[o + 5]);
            unsigned Ce3 = packbf(pv[o + 6], pv[o + 7]);
            unsigned Co0 = packbf(pv[o + 8], pv[o + 9]);
            unsigned Co1 = packbf(pv[o + 10], pv[o + 11]);
            unsigned Co2 = packbf(pv[o + 12], pv[o + 13]);
            unsigned Co3 = packbf(pv[o + 14], pv[o + 15]);
            unsigned Xe0 = (unsigned)__shfl_xor((int)Ce0, 32);
            unsigned Xe1 = (unsigned)__shfl_xor((int)Ce1, 32);
            unsigned Xe2 = (unsigned)__shfl_xor((int)Ce2, 32);
            unsigned Xe3 = (unsigned)__shfl_xor((int)Ce3, 32);
            unsigned Xo0 = (unsigned)__shfl_xor((int)Co0, 32);
            unsigned Xo1 = (unsigned)__shfl_xor((int)Co1, 32);
            unsigned Xo2 = (unsigned)__shfl_xor((int)Co2, 32);
            unsigned Xo3 = (unsigned)__shfl_xor((int)Co3, 32);
            PW we, wo;
            we.u[0] = hi ? Xe2 : Ce0;
            we.u[1] = hi ? Xe3 : Ce1;
            we.u[2] = hi ? Ce2 : Xe0;
            we.u[3] = hi ? Ce3 : Xe1;
            wo.u[0] = hi ? Xo2 : Co0;
            wo.u[1] = hi ? Xo3 : Co1;
            wo.u[2] = hi ? Co2 : Xo0;
            wo.u[3] = hi ? Co3 : Xo1;
            pfrag[mb * 2 + 0] = we.v;
            pfrag[mb * 2 + 1] = wo.v;
        }

        // ---- PV: D[c,l] += V[c,m] * P[m,l] ; 4 k-steps x 8 c-blocks ----
        const char* Vc = Vbase_l + cur * 32768;
#pragma unroll
        for (int ks2 = 0; ks2 < 4; ++ks2) {
            int cb2 = ks2 * 32 + hi * 16;
#pragma unroll
            for (int cb = 0; cb < 8; ++cb) {
                int c = cb * 32 + l31;
                bf16x8 a = *reinterpret_cast<const bf16x8*>(Vc + c * 128 + (cb2 ^ ((c & 7) << 4)));
                acc[cb] = __builtin_amdgcn_mfma_f32_32x32x16_bf16(a, pfrag[ks2], acc[cb], 0, 0, 0);
            }
        }

        // ---- publish: my DMAs landed; all waves done before buffer swap ----
        asm volatile("s_waitcnt vmcnt(0)" ::: "memory");
        __builtin_amdgcn_s_barrier();
        asm volatile("" ::: "memory");
    }

    // ---- epilogue: out[b][c][l] = acc/l_run * tanh(gate) + x ----
    float gt = tanhf(gate[0]);
    float inv = gt / l_run;
    const float* xp = x + (size_t)b * C_ * L_;
    float* op = out + (size_t)b * C_ * L_;
    int lcol = l0w + l31;
#pragma unroll
    for (int cb = 0; cb < 8; ++cb)
#pragma unroll
        for (int r = 0; r < 16; ++r) {
            int c = cb * 32 + (r & 3) + 8 * (r >> 2) + 4 * hi;
            size_t idx = (size_t)c * L_ + lcol;
            op[idx] = acc[cb][r] * inv + xp[idx];
        }
}

extern "C" void kernel_launch(void* const* d_in, const int* in_sizes, int n_in,
                              void* d_out, int out_size, void* d_ws, size_t ws_size,
                              hipStream_t stream) {
    const float* x    = (const float*)d_in[0];
    const float* Wq   = (const float*)d_in[1];
    const float* bq   = (const float*)d_in[2];
    const float* Wk   = (const float*)d_in[3];
    const float* bk   = (const float*)d_in[4];
    const float* Wv   = (const float*)d_in[5];
    const float* bv   = (const float*)d_in[6];
    const float* gate = (const float*)d_in[7];
    float* out = (float*)d_out;

    char* ws = (char*)d_ws;
    const size_t szW   = (size_t)C_ * C_ * 2;          // 131072
    const size_t szXbt = (size_t)B_ * L_ * C_ * 2;     // 16777216
    const size_t szXh  = (size_t)B_ * M_ * C_ * 2;     // 8388608
    bf16_t* Wqb  = (bf16_t*)(ws);
    bf16_t* Wkb  = (bf16_t*)(ws + szW);
    bf16_t* Wvb  = (bf16_t*)(ws + 2 * szW);
    bf16_t* xbt  = (bf16_t*)(ws + 3 * szW);
    bf16_t* xhbt = (bf16_t*)(ws + 3 * szW + szXbt);
    bf16_t* qb   = (bf16_t*)(ws + 3 * szW + szXbt + szXh);
    bf16_t* kb   = (bf16_t*)(ws + 3 * szW + 2 * szXbt + szXh);
    bf16_t* vb   = (bf16_t*)(ws + 3 * szW + 2 * szXbt + 2 * szXh);

    conv_w_kernel<<<768, 256, 0, stream>>>(Wq, Wk, Wv, Wqb, Wkb, Wvb);
    prep_x_kernel<<<dim3(L_ / 64, C_ / 64, B_), 256, 0, stream>>>(x, xbt, xhbt);
    proj_nk_kernel<<<dim3(L_ / 64, B_), 256, 0, stream>>>(xbt, Wqb, bq, qb, L_);
    proj_nk_kernel<<<dim3(M_ / 64, B_), 256, 0, stream>>>(xhbt, Wkb, bk, kb, M_);
    proj_v_kernel<<<dim3(M_ / 256, C_ / 64, B_), 256, 0, stream>>>(xhbt, Wvb, bv, vb);
    attn_kernel<<<256, 256, 0, stream>>>(qb, kb, vb, x, gate, out);
}